// Round 9
// baseline (209.433 us; speedup 1.0000x reference)
//
#include <hip/hip_runtime.h>

#define OBS_LEN 8
#define PRED_LEN 12
#define TILE_B 128
#define NTHREADS 256

typedef __attribute__((ext_vector_type(8))) short short8;  // 8 bf16
typedef __attribute__((ext_vector_type(4))) float floatx4;
typedef __attribute__((ext_vector_type(2))) float floatx2;
typedef __attribute__((ext_vector_type(4))) unsigned int u32x4;
typedef __attribute__((ext_vector_type(2))) unsigned int u32x2;
typedef unsigned short u16;
typedef unsigned int u32;

#define L2E 1.442695040888963f

__device__ __forceinline__ u16 f2bf(float f) {
  __bf16 b = (__bf16)f;
  return __builtin_bit_cast(u16, b);
}

#if __has_builtin(__builtin_amdgcn_exp2f)
__device__ __forceinline__ float fexp2_(float x) { return __builtin_amdgcn_exp2f(x); }
#else
__device__ __forceinline__ float fexp2_(float x) { return exp2f(x); }
#endif
__device__ __forceinline__ floatx2 exp2v(floatx2 x) {
  floatx2 r;
  r.x = fexp2_(x.x);
  r.y = fexp2_(x.y);
  return r;
}
#if __has_builtin(__builtin_amdgcn_rcpf)
__device__ __forceinline__ floatx2 rcp2(floatx2 x) {  // raw v_rcp ~1ulp
  floatx2 r;
  r.x = __builtin_amdgcn_rcpf(x.x);
  r.y = __builtin_amdgcn_rcpf(x.y);
  return r;
}
#else
__device__ __forceinline__ floatx2 rcp2(floatx2 x) {
  return floatx2{1.0f / x.x, 1.0f / x.y};
}
#endif

__device__ __forceinline__ floatx4 mfma_bf(short8 a, short8 b, floatx4 c) {
  return __builtin_amdgcn_mfma_f32_16x16x32_bf16(a, b, c, 0, 0, 0);
}

// short8 with elements 0,1 = the two bf16 halves of a, rest zero (k=0,1 frag).
__device__ __forceinline__ short8 frag_lo(u32 a) {
  return __builtin_bit_cast(short8, u32x4{a, 0u, 0u, 0u});
}

// Rank-2 input fold for gate row g: A_r[g] = sum_e W_ih[g,e]*emb_w[e,r],
// B0[g] = sum_e W_ih[g,e]*emb_b[e].
__device__ __forceinline__ void fold_rank2(const float* __restrict__ wr,
                                           const float* __restrict__ emb_w,
                                           const float* __restrict__ emb_b,
                                           float& A0, float& A1, float& B0) {
  A0 = A1 = B0 = 0.f;
#pragma unroll
  for (int e4 = 0; e4 < 16; ++e4) {
    const floatx4 w = *(const floatx4*)(wr + e4 * 4);
    const floatx4 m0 = *(const floatx4*)(emb_w + e4 * 8);      // e0,e1 pairs
    const floatx4 m1 = *(const floatx4*)(emb_w + e4 * 8 + 4);  // e2,e3 pairs
    const floatx4 bb = *(const floatx4*)(emb_b + e4 * 4);
    A0 += w[0] * m0[0] + w[1] * m0[2] + w[2] * m1[0] + w[3] * m1[2];
    A1 += w[0] * m0[1] + w[1] * m0[3] + w[2] * m1[1] + w[3] * m1[3];
    B0 += w[0] * bb[0] + w[1] * bb[1] + w[2] * bb[2] + w[3] * bb[3];
  }
}

// Stage W (f32 row-major [256][64]) into frag-ready LDS: slot (tile,kf,lane)
// holds A-frag 16B for row=lane&15 of tile, k = kf*32 + (lane>>4)*8 + j.
__device__ __forceinline__ void stage_w(const float* __restrict__ W,
                                        u16* __restrict__ wS, int tid) {
  for (int slot = tid; slot < 2048; slot += NTHREADS) {
    const int lane = slot & 63, kf = (slot >> 6) & 1, tile = slot >> 7;
    const int g = lane >> 4, l16 = lane & 15;
    const int gate = (tile >> 2) * 64 + (tile & 3) * 16 + l16;
    const float* src = W + gate * 64 + kf * 32 + g * 8;
    const floatx4 w0 = *(const floatx4*)src;
    const floatx4 w1 = *(const floatx4*)(src + 4);
    short8 a;
#pragma unroll
    for (int j = 0; j < 4; ++j) {
      a[j] = (short)f2bf(w0[j]);
      a[j + 4] = (short)f2bf(w1[j]);
    }
    *(short8*)(wS + slot * 8) = a;
  }
}

// Same, but W_eff = Whh + A0⊗h2p0 + A1⊗h2p1 (f32 math, ONE bf16 rounding).
__device__ __forceinline__ void stage_weff(const float* __restrict__ Whh,
                                           const float* __restrict__ dA0S,
                                           const float* __restrict__ dA1S,
                                           const float* __restrict__ hw0,
                                           const float* __restrict__ hw1,
                                           u16* __restrict__ wS, int tid) {
  for (int slot = tid; slot < 2048; slot += NTHREADS) {
    const int lane = slot & 63, kf = (slot >> 6) & 1, tile = slot >> 7;
    const int g = lane >> 4, l16 = lane & 15;
    const int gate = (tile >> 2) * 64 + (tile & 3) * 16 + l16;
    const int k0 = kf * 32 + g * 8;
    const float a0 = dA0S[gate], a1 = dA1S[gate];
    const float* src = Whh + gate * 64 + k0;
    const floatx4 w0 = *(const floatx4*)src;
    const floatx4 w1 = *(const floatx4*)(src + 4);
    const floatx4 p00 = *(const floatx4*)(hw0 + k0);
    const floatx4 p01 = *(const floatx4*)(hw0 + k0 + 4);
    const floatx4 p10 = *(const floatx4*)(hw1 + k0);
    const floatx4 p11 = *(const floatx4*)(hw1 + k0 + 4);
    short8 a;
#pragma unroll
    for (int j = 0; j < 4; ++j) {
      a[j] = (short)f2bf(w0[j] + a0 * p00[j] + a1 * p10[j]);
      a[j + 4] = (short)f2bf(w1[j] + a0 * p01[j] + a1 * p11[j]);
    }
    *(short8*)(wS + slot * 8) = a;
  }
}

// Load all 32 weight fragments LDS -> registers (once per weight phase).
// All indices compile-time (full unroll) -> stays in registers, no scratch.
__device__ __forceinline__ void load_wf(const u16* __restrict__ wp,
                                        short8 (&wf)[16][2]) {
#pragma unroll
  for (int tile = 0; tile < 16; ++tile)
#pragma unroll
    for (int kf = 0; kf < 2; ++kf)
      wf[tile][kf] = *(const short8*)(wp + (tile * 2 + kf) * 512);
}

// Gate nonlinearity + swizzled h write for one 16-unit group x 16 samples
// (verbatim math from the proven kernel; cc = cell state).
__device__ __forceinline__ void nonlin_store_ut(const floatx4 (&acc)[4],
                                                floatx4& cc,
                                                u16* __restrict__ wrow,
                                                int g, int ut, int sw) {
  u32 hpk[2];
#pragma unroll
  for (int p = 0; p < 2; ++p) {
    const floatx2 iv = {acc[0][2 * p], acc[0][2 * p + 1]};
    const floatx2 fv = {acc[1][2 * p], acc[1][2 * p + 1]};
    const floatx2 gv = {acc[2][2 * p], acc[2][2 * p + 1]};
    const floatx2 ov = {acc[3][2 * p], acc[3][2 * p + 1]};
    const floatx2 ei = exp2v(iv * -L2E);
    const floatx2 ef = exp2v(fv * -L2E);
    const floatx2 eg = exp2v(gv * (2.0f * L2E));
    const floatx2 eo = exp2v(ov * -L2E);
    const floatx2 A = ei + 1.0f;   // 1/sig(i)
    const floatx2 F = ef + 1.0f;   // 1/sig(f)
    const floatx2 Bg = eg + 1.0f;  // tanh(g) = (eg-1)/Bg
    const floatx2 P = A * Bg;
    const floatx2 cold = {cc[2 * p], cc[2 * p + 1]};
    const floatx2 num = cold * P + (eg - 1.0f) * F;
    const floatx2 cn = num * rcp2(F * P);
    cc[2 * p] = cn.x;
    cc[2 * p + 1] = cn.y;
    const floatx2 ec = exp2v(cn * (2.0f * L2E));
    const floatx2 h = (ec - 1.0f) * rcp2((eo + 1.0f) * (ec + 1.0f));
    hpk[p] = (u32)f2bf(h.x) | ((u32)f2bf(h.y) << 16);
  }
  *(u32x2*)(wrow + (((ut * 2 + (g >> 1)) ^ sw) * 8) + (g & 1) * 4) =
      u32x2{hpk[0], hpk[1]};
}

// One full cell step for this wave's 32 samples (2 n-groups x 4 ut-groups).
// Weights come from REGISTERS (wf) -- zero LDS weight traffic in the loop.
// PH: 0 = pos rank-2 term (enc/dec0), 1 = folded decoder. REL: emit
// rel = h @ h2p^T + pb via 2 MFMAs per n-group straight to global.
template <int PH, int REL>
__device__ __forceinline__ void step_all(
    const short8 (&wf)[16][2], floatx4 (&c)[8], u16* __restrict__ hw,
    const u32* __restrict__ pafp, const float* __restrict__ biasp,
    const u32* __restrict__ posrow, short8 xf0, short8 xf1,
    float hb2p0, float hb2p1, float* __restrict__ outp, long sbase,
    int wv, int g, int l16, int sw8) {
#pragma unroll
  for (int n = 0; n < 2; ++n) {
    u16* wrow = hw + (n * 16 + l16) * 64;
    const short8 hb0 = *(const short8*)(wrow + ((g ^ sw8) * 8));
    const short8 hb1 = *(const short8*)(wrow + (((4 + g) ^ sw8) * 8));
    short8 pfv = short8{0, 0, 0, 0, 0, 0, 0, 0};
    if (PH == 0) {
      const u32 pp = (g == 0) ? posrow[wv * 32 + n * 16 + l16] : 0u;
      pfv = frag_lo(pp);
    }
    if (REL) {
      floatx4 ar = mfma_bf(xf0, hb0, floatx4{0.f, 0.f, 0.f, 0.f});
      ar = mfma_bf(xf1, hb1, ar);
      if (g == 0)
        *(floatx2*)(outp + (sbase + n * 16 + l16) * 2) =
            floatx2{ar[0] + hb2p0, ar[1] + hb2p1};
    }
#pragma unroll
    for (int ut = 0; ut < 4; ++ut) {
      floatx4 acc[4];
#pragma unroll
      for (int tg = 0; tg < 4; ++tg) {
        const int tile = tg * 4 + ut;
        const floatx4 biasv =
            *(const floatx4*)(biasp + tg * 64 + ut * 16 + g * 4);
        if (PH == 0) {
          const u32 pa = (g == 0) ? pafp[tile * 16 + l16] : 0u;
          acc[tg] = mfma_bf(frag_lo(pa), pfv, biasv);  // pos term, matrix pipe
        } else {
          acc[tg] = biasv;
        }
        acc[tg] = mfma_bf(wf[tile][1], hb1, acc[tg]);
        acc[tg] = mfma_bf(wf[tile][0], hb0, acc[tg]);
      }
      nonlin_store_ut(acc, c[n * 4 + ut], wrow, g, ut, sw8);
      __builtin_amdgcn_sched_barrier(0);
    }
  }
}

// R8 post-mortem: 58% VALUBusy ceiling was LDS BW -- 16 waves/CU re-reading
// 32KB of weight frags EVERY step (~864 b128/CU/step x 12cy ~= the wall).
// Fix: 2 waves/SIMD (256-VGPR budget) -> ALL 32 weight frags live in
// registers (128 VGPR), loaded once per weight phase. Each wave owns 32
// samples (2x VALU work/step) so 2 waves/SIMD still feed the pipe.
// Steady-state LDS = bias/paf/h only (~20 reads/wave-step, 4x headroom).
// Barrier-free recurrence (sample-ownership, wave-private h strips) kept.
__global__ void __launch_bounds__(NTHREADS, 2)
lstm_kernel(const float* __restrict__ obs_rel,
            const float* __restrict__ enc_emb_w, const float* __restrict__ enc_emb_b,
            const float* __restrict__ enc_w_ih, const float* __restrict__ enc_w_hh,
            const float* __restrict__ enc_b_ih, const float* __restrict__ enc_b_hh,
            const float* __restrict__ dec_emb_w, const float* __restrict__ dec_emb_b,
            const float* __restrict__ dec_w_ih, const float* __restrict__ dec_w_hh,
            const float* __restrict__ dec_b_ih, const float* __restrict__ dec_b_hh,
            const float* __restrict__ h2p_w, const float* __restrict__ h2p_b,
            float* __restrict__ out, int batch) {
  __shared__ __align__(16) u16 wS[16384];           // 32KB frag-formatted weights
  __shared__ __align__(16) u16 hP[4 * 2048];        // 16KB: 4 waves x 32 rows
  __shared__ __align__(16) float biasS[3][256];     // enc, dec0, dec-folded
  __shared__ __align__(16) u32 pafS[2][256];        // packed (A0,A1) [tile][l16]
  __shared__ __align__(16) u32 posP[OBS_LEN * TILE_B];  // packed bf16 pos pairs
  __shared__ __align__(16) float hw0S[64], hw1S[64];
  __shared__ __align__(16) float dA0S[256], dA1S[256];

  const int tid = threadIdx.x;
  const int wv = tid >> 6, lane = tid & 63;
  const int g = lane >> 4, l16 = lane & 15;
  const long S0 = (long)blockIdx.x * TILE_B;

  // ---- prologue staging
  for (int i = tid; i < OBS_LEN * TILE_B; i += NTHREADS) {
    const int t = i >> 7, s = i & 127;
    const floatx2 pp = *(const floatx2*)(obs_rel + (long)t * batch * 2 + (S0 + s) * 2);
    posP[i] = (u32)f2bf(pp.x) | ((u32)f2bf(pp.y) << 16);
  }
  if (tid < 64) {
    hw0S[tid] = h2p_w[tid];
    hw1S[tid] = h2p_w[64 + tid];
  }
  const float hb2p0 = h2p_b[0], hb2p1 = h2p_b[1];
  {
    const int t = tid >> 6, u6 = tid & 63;
    const int pidx = (t * 4 + (u6 >> 4)) * 16 + (u6 & 15);
    float A0, A1, B0;
    fold_rank2(enc_w_ih + tid * 64, enc_emb_w, enc_emb_b, A0, A1, B0);
    pafS[0][pidx] = (u32)f2bf(A0) | ((u32)f2bf(A1) << 16);
    biasS[0][tid] = enc_b_ih[tid] + enc_b_hh[tid] + B0;
    fold_rank2(dec_w_ih + tid * 64, dec_emb_w, dec_emb_b, A0, A1, B0);
    pafS[1][pidx] = (u32)f2bf(A0) | ((u32)f2bf(A1) << 16);
    dA0S[tid] = A0;
    dA1S[tid] = A1;
    const float db = dec_b_ih[tid] + dec_b_hh[tid] + B0;
    biasS[1][tid] = db;                                  // dec step 0
    biasS[2][tid] = db + A0 * hb2p0 + A1 * hb2p1;        // folded steps
  }
  stage_w(enc_w_hh, wS, tid);
  for (int i = tid; i < 4096; i += NTHREADS) ((u32*)hP)[i] = 0;  // h0 = 0
  __syncthreads();

  u16* hw = hP + wv * 2048;             // this wave's private 32-row h strip
  const u16* wp = wS + lane * 8;        // frag base (lane*16 bytes)
  const int sw8 = l16 & 7;
  const long sbase = S0 + wv * 32;

  short8 wf[16][2];
  load_wf(wp, wf);                      // encoder weights -> registers
  floatx4 c[8];
#pragma unroll
  for (int i = 0; i < 8; ++i) c[i] = floatx4{0.f, 0.f, 0.f, 0.f};
  const short8 z8 = short8{0, 0, 0, 0, 0, 0, 0, 0};

  // ---- encoder: 8 barrier-free steps (weights in regs)
#pragma unroll 1
  for (int t = 0; t < OBS_LEN; ++t) {
    step_all<0, 0>(wf, c, hw, &pafS[0][0], &biasS[0][0], posP + t * TILE_B,
                   z8, z8, 0.f, 0.f, out, sbase, wv, g, l16, sw8);
  }

  // ---- decoder step 0: x0 = lin(pos7), plain W_hh_dec, c reset
  __syncthreads();                      // all waves done with W_enc (regs hold it;
  stage_w(dec_w_hh, wS, tid);           //  barrier protects wS overwrite ordering)
  __syncthreads();
  load_wf(wp, wf);
#pragma unroll
  for (int i = 0; i < 8; ++i) c[i] = floatx4{0.f, 0.f, 0.f, 0.f};
  step_all<0, 0>(wf, c, hw, &pafS[1][0], &biasS[1][0], posP + 7 * TILE_B,
                 z8, z8, 0.f, 0.f, out, sbase, wv, g, l16, sw8);
  __syncthreads();                      // all waves done reading W_dec
  stage_weff(dec_w_hh, dA0S, dA1S, hw0S, hw1S, wS, tid);
  __syncthreads();
  load_wf(wp, wf);                      // W_eff -> registers

  // rel A-fragments: rows 0/1 = h2p rows (bf16), rest zero
  short8 xf0, xf1;
#pragma unroll
  for (int kf = 0; kf < 2; ++kf) {
    const int kb = kf * 32 + g * 8;
    short8 a;
#pragma unroll
    for (int j = 0; j < 8; ++j) {
      const float r = (l16 == 0) ? hw0S[kb + j] : (l16 == 1) ? hw1S[kb + j] : 0.f;
      a[j] = (short)f2bf(r);
    }
    if (kf == 0) xf0 = a; else xf1 = a;
  }

  // ---- folded decoder steps 1..11: barrier-free; rel_{j-1} straight to HBM
#pragma unroll 1
  for (int j = 1; j < PRED_LEN; ++j) {
    step_all<1, 1>(wf, c, hw, &pafS[1][0], &biasS[2][0], posP,
                   xf0, xf1, hb2p0, hb2p1,
                   out + (long)(j - 1) * batch * 2, sbase, wv, g, l16, sw8);
  }

  // ---- trailing output: rel_11 from h_12
#pragma unroll
  for (int n = 0; n < 2; ++n) {
    const u16* hr = hw + (n * 16 + l16) * 64;
    const short8 hb0 = *(const short8*)(hr + ((g ^ sw8) * 8));
    const short8 hb1 = *(const short8*)(hr + (((4 + g) ^ sw8) * 8));
    floatx4 ar = mfma_bf(xf0, hb0, floatx4{0.f, 0.f, 0.f, 0.f});
    ar = mfma_bf(xf1, hb1, ar);
    if (g == 0)
      *(floatx2*)(out + (long)(PRED_LEN - 1) * batch * 2 +
                  (sbase + n * 16 + l16) * 2) =
          floatx2{ar[0] + hb2p0, ar[1] + hb2p1};
  }
}

extern "C" void kernel_launch(void* const* d_in, const int* in_sizes, int n_in,
                              void* d_out, int out_size, void* d_ws, size_t ws_size,
                              hipStream_t stream) {
  const float* obs_rel = (const float*)d_in[1];
  const int batch = in_sizes[1] / (OBS_LEN * 2);  // 65536

  const int blocks = batch / TILE_B;  // 512 = exactly 2 blocks per CU
  hipLaunchKernelGGL(lstm_kernel, dim3(blocks), dim3(NTHREADS), 0, stream,
                     obs_rel,
                     (const float*)d_in[2], (const float*)d_in[3],
                     (const float*)d_in[4], (const float*)d_in[5],
                     (const float*)d_in[6], (const float*)d_in[7],
                     (const float*)d_in[8], (const float*)d_in[9],
                     (const float*)d_in[10], (const float*)d_in[11],
                     (const float*)d_in[12], (const float*)d_in[13],
                     (const float*)d_in[14], (const float*)d_in[15],
                     (float*)d_out, batch);
}

// Round 10
// 194.291 us; speedup vs baseline: 1.0779x; 1.0779x over previous
//
#include <hip/hip_runtime.h>

#define OBS_LEN 8
#define PRED_LEN 12
#define TILE_B 128
#define NTHREADS 512

typedef __attribute__((ext_vector_type(8))) short short8;  // 8 bf16
typedef __attribute__((ext_vector_type(4))) float floatx4;
typedef __attribute__((ext_vector_type(2))) float floatx2;
typedef __attribute__((ext_vector_type(4))) unsigned int u32x4;
typedef __attribute__((ext_vector_type(2))) unsigned int u32x2;
typedef unsigned short u16;
typedef unsigned int u32;

#define L2E 1.442695040888963f

__device__ __forceinline__ u16 f2bf(float f) {
  __bf16 b = (__bf16)f;
  return __builtin_bit_cast(u16, b);
}

#if __has_builtin(__builtin_amdgcn_exp2f)
__device__ __forceinline__ float fexp2_(float x) { return __builtin_amdgcn_exp2f(x); }
#else
__device__ __forceinline__ float fexp2_(float x) { return exp2f(x); }
#endif
__device__ __forceinline__ floatx2 exp2v(floatx2 x) {
  floatx2 r;
  r.x = fexp2_(x.x);
  r.y = fexp2_(x.y);
  return r;
}
#if __has_builtin(__builtin_amdgcn_rcpf)
__device__ __forceinline__ floatx2 rcp2(floatx2 x) {  // raw v_rcp ~1ulp
  floatx2 r;
  r.x = __builtin_amdgcn_rcpf(x.x);
  r.y = __builtin_amdgcn_rcpf(x.y);
  return r;
}
#else
__device__ __forceinline__ floatx2 rcp2(floatx2 x) {
  return floatx2{1.0f / x.x, 1.0f / x.y};
}
#endif

__device__ __forceinline__ floatx4 mfma_bf(short8 a, short8 b, floatx4 c) {
  return __builtin_amdgcn_mfma_f32_16x16x32_bf16(a, b, c, 0, 0, 0);
}

// short8 with elements 0,1 = the two bf16 halves of a, rest zero (k=0,1 frag).
__device__ __forceinline__ short8 frag_lo(u32 a) {
  return __builtin_bit_cast(short8, u32x4{a, 0u, 0u, 0u});
}

// Rank-2 input fold for gate row g: A_r[g] = sum_e W_ih[g,e]*emb_w[e,r],
// B0[g] = sum_e W_ih[g,e]*emb_b[e].
__device__ __forceinline__ void fold_rank2(const float* __restrict__ wr,
                                           const float* __restrict__ emb_w,
                                           const float* __restrict__ emb_b,
                                           float& A0, float& A1, float& B0) {
  A0 = A1 = B0 = 0.f;
#pragma unroll
  for (int e4 = 0; e4 < 16; ++e4) {
    const floatx4 w = *(const floatx4*)(wr + e4 * 4);
    const floatx4 m0 = *(const floatx4*)(emb_w + e4 * 8);      // e0,e1 pairs
    const floatx4 m1 = *(const floatx4*)(emb_w + e4 * 8 + 4);  // e2,e3 pairs
    const floatx4 bb = *(const floatx4*)(emb_b + e4 * 4);
    A0 += w[0] * m0[0] + w[1] * m0[2] + w[2] * m1[0] + w[3] * m1[2];
    A1 += w[0] * m0[1] + w[1] * m0[3] + w[2] * m1[1] + w[3] * m1[3];
    B0 += w[0] * bb[0] + w[1] * bb[1] + w[2] * bb[2] + w[3] * bb[3];
  }
}

// Stage W (f32 row-major [256][64]) into frag-ready LDS: slot (tile,kf,lane)
// holds A-frag 16B for row=lane&15 of tile, k = kf*32 + (lane>>4)*8 + j.
__device__ __forceinline__ void stage_w(const float* __restrict__ W,
                                        u16* __restrict__ wS, int tid) {
  for (int slot = tid; slot < 2048; slot += NTHREADS) {
    const int lane = slot & 63, kf = (slot >> 6) & 1, tile = slot >> 7;
    const int g = lane >> 4, l16 = lane & 15;
    const int gate = (tile >> 2) * 64 + (tile & 3) * 16 + l16;
    const float* src = W + gate * 64 + kf * 32 + g * 8;
    const floatx4 w0 = *(const floatx4*)src;
    const floatx4 w1 = *(const floatx4*)(src + 4);
    short8 a;
#pragma unroll
    for (int j = 0; j < 4; ++j) {
      a[j] = (short)f2bf(w0[j]);
      a[j + 4] = (short)f2bf(w1[j]);
    }
    *(short8*)(wS + slot * 8) = a;
  }
}

// Same, but W_eff = Whh + A0⊗h2p0 + A1⊗h2p1 (f32 math, ONE bf16 rounding).
__device__ __forceinline__ void stage_weff(const float* __restrict__ Whh,
                                           const float* __restrict__ dA0S,
                                           const float* __restrict__ dA1S,
                                           const float* __restrict__ hw0,
                                           const float* __restrict__ hw1,
                                           u16* __restrict__ wS, int tid) {
  for (int slot = tid; slot < 2048; slot += NTHREADS) {
    const int lane = slot & 63, kf = (slot >> 6) & 1, tile = slot >> 7;
    const int g = lane >> 4, l16 = lane & 15;
    const int gate = (tile >> 2) * 64 + (tile & 3) * 16 + l16;
    const int k0 = kf * 32 + g * 8;
    const float a0 = dA0S[gate], a1 = dA1S[gate];
    const float* src = Whh + gate * 64 + k0;
    const floatx4 w0 = *(const floatx4*)src;
    const floatx4 w1 = *(const floatx4*)(src + 4);
    const floatx4 p00 = *(const floatx4*)(hw0 + k0);
    const floatx4 p01 = *(const floatx4*)(hw0 + k0 + 4);
    const floatx4 p10 = *(const floatx4*)(hw1 + k0);
    const floatx4 p11 = *(const floatx4*)(hw1 + k0 + 4);
    short8 a;
#pragma unroll
    for (int j = 0; j < 4; ++j) {
      a[j] = (short)f2bf(w0[j] + a0 * p00[j] + a1 * p10[j]);
      a[j + 4] = (short)f2bf(w1[j] + a0 * p01[j] + a1 * p11[j]);
    }
    *(short8*)(wS + slot * 8) = a;
  }
}

// Cache tiles 0..7 (tg=0,1) in registers: 8 tiles x 2 kf x 4 VGPR = 64 VGPRs.
// Fully unrolled, compile-time indices -> registers, no scratch (R9 lesson:
// ALL 16 tiles = 128 VGPRs spills; half fits the (512,4) 128-VGPR budget).
__device__ __forceinline__ void load_wfhalf(const u16* __restrict__ wp,
                                            short8 (&wfr)[8][2]) {
#pragma unroll
  for (int tile = 0; tile < 8; ++tile)
#pragma unroll
    for (int kf = 0; kf < 2; ++kf)
      wfr[tile][kf] = *(const short8*)(wp + (tile * 2 + kf) * 512);
}

// Gate nonlinearity + wave-private swizzled h write for one ut-group
// (verbatim math from the proven kernel; cc = cell state, units ut*16+4g+r).
__device__ __forceinline__ void nonlin_store_ut(const floatx4 (&acc)[4],
                                                floatx4& cc,
                                                u16* __restrict__ wrh,
                                                int l16, int g, int ut) {
  const int sw = l16 & 7;
  u32 hpk[2];
#pragma unroll
  for (int p = 0; p < 2; ++p) {
    const floatx2 iv = {acc[0][2 * p], acc[0][2 * p + 1]};
    const floatx2 fv = {acc[1][2 * p], acc[1][2 * p + 1]};
    const floatx2 gv = {acc[2][2 * p], acc[2][2 * p + 1]};
    const floatx2 ov = {acc[3][2 * p], acc[3][2 * p + 1]};
    const floatx2 ei = exp2v(iv * -L2E);
    const floatx2 ef = exp2v(fv * -L2E);
    const floatx2 eg = exp2v(gv * (2.0f * L2E));
    const floatx2 eo = exp2v(ov * -L2E);
    const floatx2 A = ei + 1.0f;   // 1/sig(i)
    const floatx2 F = ef + 1.0f;   // 1/sig(f)
    const floatx2 Bg = eg + 1.0f;  // tanh(g) = (eg-1)/Bg
    const floatx2 P = A * Bg;
    const floatx2 cold = {cc[2 * p], cc[2 * p + 1]};
    const floatx2 num = cold * P + (eg - 1.0f) * F;
    const floatx2 cn = num * rcp2(F * P);
    cc[2 * p] = cn.x;
    cc[2 * p + 1] = cn.y;
    const floatx2 ec = exp2v(cn * (2.0f * L2E));
    const floatx2 h = (ec - 1.0f) * rcp2((eo + 1.0f) * (ec + 1.0f));
    hpk[p] = (u32)f2bf(h.x) | ((u32)f2bf(h.y) << 16);
  }
  *(u32x2*)(wrh + l16 * 64 + (((ut * 2 + (g >> 1)) ^ sw) * 8) + (g & 1) * 4) =
      u32x2{hpk[0], hpk[1]};
}

// One ut-group (units ut*16..+15, this wave's 16 samples): 4 gate-tiles.
// Tiles tg=0,1 come from REGISTERS (wfr), tg=2,3 stream from LDS -- halves
// the per-step LDS weight BW that capped R8 at 58% VALUBusy.
// PH: 0 = pos-term (enc/dec0), 1 = folded decoder (no pos term).
template <int PH>
__device__ __forceinline__ void ut_group(int ut, floatx4& cc,
                                         short8 hb0, short8 hb1, short8 pfv,
                                         const short8 (&wfr)[8][2],
                                         const u16* __restrict__ wp,
                                         const u32* __restrict__ pafp,
                                         const float* __restrict__ biasp,
                                         u16* __restrict__ wrh,
                                         int g, int l16) {
  floatx4 acc[4];
#pragma unroll
  for (int tg = 0; tg < 4; ++tg) {
    const int tile = tg * 4 + ut;
    const floatx4 biasv = *(const floatx4*)(biasp + tg * 64 + ut * 16 + g * 4);
    if (PH == 0) {
      const u32 pa = (g == 0) ? pafp[tile * 16 + l16] : 0u;
      acc[tg] = mfma_bf(frag_lo(pa), pfv, biasv);  // pos term on matrix pipe
    } else {
      acc[tg] = biasv;
    }
    if (tg < 2) {
      acc[tg] = mfma_bf(wfr[tile][1], hb1, acc[tg]);
      acc[tg] = mfma_bf(wfr[tile][0], hb0, acc[tg]);
    } else {
      acc[tg] = mfma_bf(*(const short8*)(wp + (tile * 2 + 1) * 512), hb1, acc[tg]);
      acc[tg] = mfma_bf(*(const short8*)(wp + (tile * 2 + 0) * 512), hb0, acc[tg]);
    }
  }
  nonlin_store_ut(acc, cc, wrh, l16, g, ut);
}

// Sample-ownership (R8 structure + half-reg weights): each wave owns 16
// samples, h in a wave-PRIVATE 2KB LDS strip -> no __syncthreads in the 21
// recurrence steps. R8's ceiling was LDS weight streaming (~864 b128/CU/step);
// caching tiles 0..7 in 64 VGPRs halves that (R9 showed all 16 = spill).
// TILE_B=128, 512 blocks = exactly 2 blocks/CU, 16 waves/CU, zero tail.
__global__ void __launch_bounds__(NTHREADS, 4)
lstm_kernel(const float* __restrict__ obs_rel,
            const float* __restrict__ enc_emb_w, const float* __restrict__ enc_emb_b,
            const float* __restrict__ enc_w_ih, const float* __restrict__ enc_w_hh,
            const float* __restrict__ enc_b_ih, const float* __restrict__ enc_b_hh,
            const float* __restrict__ dec_emb_w, const float* __restrict__ dec_emb_b,
            const float* __restrict__ dec_w_ih, const float* __restrict__ dec_w_hh,
            const float* __restrict__ dec_b_ih, const float* __restrict__ dec_b_hh,
            const float* __restrict__ h2p_w, const float* __restrict__ h2p_b,
            float* __restrict__ out, int batch) {
  __shared__ __align__(16) u16 wS[16384];           // 32KB frag-formatted weights
  __shared__ __align__(16) u16 hP[8 * 1024];        // 16KB wave-private h strips
  __shared__ __align__(16) float biasS[3][256];     // enc, dec0, dec-folded
  __shared__ __align__(16) u32 pafS[2][256];        // packed (A0,A1) [tile][l16]
  __shared__ __align__(16) u32 posP[OBS_LEN * TILE_B];  // packed bf16 pos pairs
  __shared__ __align__(16) float hw0S[64], hw1S[64];
  __shared__ __align__(16) float dA0S[256], dA1S[256];

  const int tid = threadIdx.x;
  const int wv = tid >> 6, lane = tid & 63;
  const int g = lane >> 4, l16 = lane & 15;
  const long S0 = (long)blockIdx.x * TILE_B;

  // ---- prologue staging
  for (int i = tid; i < OBS_LEN * TILE_B; i += NTHREADS) {
    const int t = i >> 7, s = i & 127;
    const floatx2 pp = *(const floatx2*)(obs_rel + (long)t * batch * 2 + (S0 + s) * 2);
    posP[i] = (u32)f2bf(pp.x) | ((u32)f2bf(pp.y) << 16);
  }
  if (tid < 64) {
    hw0S[tid] = h2p_w[tid];
    hw1S[tid] = h2p_w[64 + tid];
  }
  const float hb2p0 = h2p_b[0], hb2p1 = h2p_b[1];
  if (tid < 256) {
    const int t = tid >> 6, u6 = tid & 63;
    const int pidx = (t * 4 + (u6 >> 4)) * 16 + (u6 & 15);
    float A0, A1, B0;
    fold_rank2(enc_w_ih + tid * 64, enc_emb_w, enc_emb_b, A0, A1, B0);
    pafS[0][pidx] = (u32)f2bf(A0) | ((u32)f2bf(A1) << 16);
    biasS[0][tid] = enc_b_ih[tid] + enc_b_hh[tid] + B0;
    fold_rank2(dec_w_ih + tid * 64, dec_emb_w, dec_emb_b, A0, A1, B0);
    pafS[1][pidx] = (u32)f2bf(A0) | ((u32)f2bf(A1) << 16);
    dA0S[tid] = A0;
    dA1S[tid] = A1;
    const float db = dec_b_ih[tid] + dec_b_hh[tid] + B0;
    biasS[1][tid] = db;                                  // dec step 0
    biasS[2][tid] = db + A0 * hb2p0 + A1 * hb2p1;        // folded steps
  }
  stage_w(enc_w_hh, wS, tid);
  for (int i = tid; i < 4096; i += NTHREADS) ((u32*)hP)[i] = 0;  // h0 = 0
  __syncthreads();

  u16* hw = hP + wv * 1024;             // this wave's private h strip
  const u16* wp = wS + lane * 8;        // frag base (lane*16 bytes)
  const int sw8 = l16 & 7;

  short8 wfr[8][2];
  load_wfhalf(wp, wfr);                 // encoder tiles 0..7 -> registers
  floatx4 c0{0.f, 0.f, 0.f, 0.f}, c1{0.f, 0.f, 0.f, 0.f};
  floatx4 c2v{0.f, 0.f, 0.f, 0.f}, c3{0.f, 0.f, 0.f, 0.f};

  // ---- encoder: 8 barrier-free steps
#pragma unroll 1
  for (int t = 0; t < OBS_LEN; ++t) {
    const u16* hr = hw + l16 * 64;
    const short8 hb0 = *(const short8*)(hr + ((g ^ sw8) * 8));
    const short8 hb1 = *(const short8*)(hr + (((4 + g) ^ sw8) * 8));
    const u32 pp = (g == 0) ? posP[t * TILE_B + wv * 16 + l16] : 0u;
    const short8 pfv = frag_lo(pp);
    ut_group<0>(0, c0, hb0, hb1, pfv, wfr, wp, &pafS[0][0], &biasS[0][0], hw, g, l16);
    __builtin_amdgcn_sched_barrier(0);
    ut_group<0>(1, c1, hb0, hb1, pfv, wfr, wp, &pafS[0][0], &biasS[0][0], hw, g, l16);
    __builtin_amdgcn_sched_barrier(0);
    ut_group<0>(2, c2v, hb0, hb1, pfv, wfr, wp, &pafS[0][0], &biasS[0][0], hw, g, l16);
    __builtin_amdgcn_sched_barrier(0);
    ut_group<0>(3, c3, hb0, hb1, pfv, wfr, wp, &pafS[0][0], &biasS[0][0], hw, g, l16);
  }

  // ---- decoder step 0: x0 = lin(pos7), plain W_hh_dec, c reset
  __syncthreads();                     // all waves done with W_enc
  stage_w(dec_w_hh, wS, tid);
  __syncthreads();
  load_wfhalf(wp, wfr);                // dec tiles 0..7 -> registers
  c0 = c1 = c2v = c3 = floatx4{0.f, 0.f, 0.f, 0.f};
  {
    const u16* hr = hw + l16 * 64;
    const short8 hb0 = *(const short8*)(hr + ((g ^ sw8) * 8));
    const short8 hb1 = *(const short8*)(hr + (((4 + g) ^ sw8) * 8));
    const u32 pp = (g == 0) ? posP[7 * TILE_B + wv * 16 + l16] : 0u;
    const short8 pfv = frag_lo(pp);
    ut_group<0>(0, c0, hb0, hb1, pfv, wfr, wp, &pafS[1][0], &biasS[1][0], hw, g, l16);
    __builtin_amdgcn_sched_barrier(0);
    ut_group<0>(1, c1, hb0, hb1, pfv, wfr, wp, &pafS[1][0], &biasS[1][0], hw, g, l16);
    __builtin_amdgcn_sched_barrier(0);
    ut_group<0>(2, c2v, hb0, hb1, pfv, wfr, wp, &pafS[1][0], &biasS[1][0], hw, g, l16);
    __builtin_amdgcn_sched_barrier(0);
    ut_group<0>(3, c3, hb0, hb1, pfv, wfr, wp, &pafS[1][0], &biasS[1][0], hw, g, l16);
  }
  __syncthreads();                     // all waves done reading W_dec
  stage_weff(dec_w_hh, dA0S, dA1S, hw0S, hw1S, wS, tid);
  __syncthreads();
  load_wfhalf(wp, wfr);                // W_eff tiles 0..7 -> registers

  // rel A-fragments: rows 0/1 = h2p rows (bf16), rest zero
  short8 xf0, xf1;
#pragma unroll
  for (int kf = 0; kf < 2; ++kf) {
    const int kb = kf * 32 + g * 8;
    short8 a;
#pragma unroll
    for (int j = 0; j < 8; ++j) {
      const float r = (l16 == 0) ? hw0S[kb + j] : (l16 == 1) ? hw1S[kb + j] : 0.f;
      a[j] = (short)f2bf(r);
    }
    if (kf == 0) xf0 = a; else xf1 = a;
  }

  // ---- folded decoder steps 1..11: barrier-free; rel_{j-1} straight to HBM
  const floatx4 zero4{0.f, 0.f, 0.f, 0.f};
#pragma unroll 1
  for (int j = 1; j < PRED_LEN; ++j) {
    const u16* hr = hw + l16 * 64;
    const short8 hb0 = *(const short8*)(hr + ((g ^ sw8) * 8));
    const short8 hb1 = *(const short8*)(hr + (((4 + g) ^ sw8) * 8));
    floatx4 ar = mfma_bf(xf0, hb0, zero4);
    ar = mfma_bf(xf1, hb1, ar);
    if (g == 0)
      *(floatx2*)(out + (long)(j - 1) * batch * 2 + (S0 + wv * 16 + l16) * 2) =
          floatx2{ar[0] + hb2p0, ar[1] + hb2p1};
    ut_group<1>(0, c0, hb0, hb1, xf0, wfr, wp, &pafS[1][0], &biasS[2][0], hw, g, l16);
    __builtin_amdgcn_sched_barrier(0);
    ut_group<1>(1, c1, hb0, hb1, xf0, wfr, wp, &pafS[1][0], &biasS[2][0], hw, g, l16);
    __builtin_amdgcn_sched_barrier(0);
    ut_group<1>(2, c2v, hb0, hb1, xf0, wfr, wp, &pafS[1][0], &biasS[2][0], hw, g, l16);
    __builtin_amdgcn_sched_barrier(0);
    ut_group<1>(3, c3, hb0, hb1, xf0, wfr, wp, &pafS[1][0], &biasS[2][0], hw, g, l16);
  }

  // ---- trailing output: rel_11 from h_12
  {
    const u16* hr = hw + l16 * 64;
    const short8 hb0 = *(const short8*)(hr + ((g ^ sw8) * 8));
    const short8 hb1 = *(const short8*)(hr + (((4 + g) ^ sw8) * 8));
    floatx4 ar = mfma_bf(xf0, hb0, zero4);
    ar = mfma_bf(xf1, hb1, ar);
    if (g == 0)
      *(floatx2*)(out + (long)(PRED_LEN - 1) * batch * 2 + (S0 + wv * 16 + l16) * 2) =
          floatx2{ar[0] + hb2p0, ar[1] + hb2p1};
  }
}

extern "C" void kernel_launch(void* const* d_in, const int* in_sizes, int n_in,
                              void* d_out, int out_size, void* d_ws, size_t ws_size,
                              hipStream_t stream) {
  const float* obs_rel = (const float*)d_in[1];
  const int batch = in_sizes[1] / (OBS_LEN * 2);  // 65536

  const int blocks = batch / TILE_B;  // 512 = exactly 2 blocks per CU
  hipLaunchKernelGGL(lstm_kernel, dim3(blocks), dim3(NTHREADS), 0, stream,
                     obs_rel,
                     (const float*)d_in[2], (const float*)d_in[3],
                     (const float*)d_in[4], (const float*)d_in[5],
                     (const float*)d_in[6], (const float*)d_in[7],
                     (const float*)d_in[8], (const float*)d_in[9],
                     (const float*)d_in[10], (const float*)d_in[11],
                     (const float*)d_in[12], (const float*)d_in[13],
                     (const float*)d_in[14], (const float*)d_in[15],
                     (float*)d_out, batch);
}